// Round 1
// baseline (554.824 us; speedup 1.0000x reference)
//
#include <hip/hip_runtime.h>

#define CHN 6
#define NN 65536
#define BB 32
#define NMODES 16

// ---------------- Kernel 1: fused RK4 ODE ----------------
// block = 256 threads, 4 contiguous points/thread -> 1024-pt extended tile,
// 28-pt halo each side (28 dyn evals each shrink validity by 1), central 968.
#define T1 256
#define P1 4
#define EXT1 (T1*P1)            // 1024
#define HALO1 28
#define TILE1 (EXT1 - 2*HALO1)  // 968
#define NTILES ((NN + TILE1 - 1) / TILE1)  // 68

__device__ __forceinline__ float fast_tanhf(float x){
    // tanh(x) = 1 - 2/(exp(2x)+1); exp(2x) = 2^(x*2*log2(e))
    float e = __builtin_amdgcn_exp2f(x * 2.885390081777926815f);
    float r = __builtin_amdgcn_rcpf(e + 1.0f);
    return 1.0f - 2.0f * r;
}

__global__ void ode_kernel(const float* __restrict__ u0,
                           const float* __restrict__ tspan,
                           const float* __restrict__ cw,
                           const float* __restrict__ cb,
                           float* __restrict__ uout)
{
    // double-buffered edge-exchange arrays (first/last point of each thread's chunk)
    __shared__ float eF[2][CHN][T1];
    __shared__ float eL[2][CHN][T1];

    const int t = threadIdx.x;
    const int tile = blockIdx.x;
    const int b = blockIdx.y;
    const int j0 = tile*TILE1 - HALO1 + t*P1;     // global index of this thread's chunk
    // chunks are 4-aligned and N%4==0 -> chunk wholly in or out of domain
    const float m = (j0 >= 0 && j0 < NN) ? 1.0f : 0.0f;

    float u[CHN][P1], s[CHN][P1], acc[CHN][P1], k[CHN][P1];

    #pragma unroll
    for (int c=0;c<CHN;c++){
        float4 v = make_float4(0.f,0.f,0.f,0.f);
        if (m != 0.0f) v = *(const float4*)(u0 + ((size_t)(b*CHN+c))*NN + j0);
        u[c][0]=v.x; u[c][1]=v.y; u[c][2]=v.z; u[c][3]=v.w;
        s[c][0]=v.x; s[c][1]=v.y; s[c][2]=v.z; s[c][3]=v.w;
    }

    int buf = 0;
    for (int st=0; st<7; ++st){
        float dt  = tspan[st+1] - tspan[st];
        float hdt = 0.5f*dt;
        float dt6 = dt*(1.0f/6.0f);
        #pragma unroll
        for (int stage=0; stage<4; ++stage){
            // publish edges of current stage input s
            #pragma unroll
            for (int c=0;c<CHN;c++){ eF[buf][c][t]=s[c][0]; eL[buf][c][t]=s[c][P1-1]; }
            __syncthreads();
            const int tl = (t==0)?0:(t-1);
            const int tr = (t==T1-1)?(T1-1):(t+1);
            float vL[CHN], vR[CHN];
            #pragma unroll
            for (int c=0;c<CHN;c++){ vL[c]=eL[buf][c][tl]; vR[c]=eF[buf][c][tr]; }
            buf ^= 1;

            // conv1d k=3 (cross-correlation, zero pad), channels 6->6, + bias
            #pragma unroll
            for (int o=0;o<CHN;o++){
                float bo = cb[o];
                #pragma unroll
                for (int j=0;j<P1;j++) k[o][j] = bo;
            }
            #pragma unroll
            for (int i=0;i<CHN;i++){
                float a0=vL[i], b0=s[i][0], b1=s[i][1], b2=s[i][2], b3=s[i][3], a4=vR[i];
                #pragma unroll
                for (int o=0;o<CHN;o++){
                    float w0=cw[(o*CHN+i)*3+0];
                    float w1=cw[(o*CHN+i)*3+1];
                    float w2=cw[(o*CHN+i)*3+2];
                    k[o][0] += w0*a0 + w1*b0 + w2*b1;
                    k[o][1] += w0*b0 + w1*b1 + w2*b2;
                    k[o][2] += w0*b1 + w1*b2 + w2*b3;
                    k[o][3] += w0*b2 + w1*b3 + w2*a4;
                }
            }
            #pragma unroll
            for (int o=0;o<CHN;o++)
                #pragma unroll
                for (int j=0;j<P1;j++)
                    k[o][j] = fast_tanhf(k[o][j]);

            // RK4 stage update (m zeroes out-of-domain points -> correct zero padding)
            if (stage==0){
                #pragma unroll
                for (int c=0;c<CHN;c++)
                    #pragma unroll
                    for (int j=0;j<P1;j++){
                        acc[c][j] = k[c][j];
                        s[c][j] = m*(u[c][j] + hdt*k[c][j]);
                    }
            } else if (stage==1){
                #pragma unroll
                for (int c=0;c<CHN;c++)
                    #pragma unroll
                    for (int j=0;j<P1;j++){
                        acc[c][j] += 2.0f*k[c][j];
                        s[c][j] = m*(u[c][j] + hdt*k[c][j]);
                    }
            } else if (stage==2){
                #pragma unroll
                for (int c=0;c<CHN;c++)
                    #pragma unroll
                    for (int j=0;j<P1;j++){
                        acc[c][j] += 2.0f*k[c][j];
                        s[c][j] = m*(u[c][j] + dt*k[c][j]);
                    }
            } else {
                #pragma unroll
                for (int c=0;c<CHN;c++)
                    #pragma unroll
                    for (int j=0;j<P1;j++){
                        u[c][j] = m*(u[c][j] + dt6*(acc[c][j] + k[c][j]));
                        s[c][j] = u[c][j];
                    }
            }
        }
    }

    // store central region [HALO1, EXT1-HALO1) -> threads 7..248, clip to N
    if (t >= HALO1/P1 && t < (EXT1-HALO1)/P1 && j0 < NN){
        #pragma unroll
        for (int c=0;c<CHN;c++){
            float4 v = make_float4(u[c][0],u[c][1],u[c][2],u[c][3]);
            *(float4*)(uout + ((size_t)(b*CHN+c))*NN + j0) = v;
        }
    }
}

// ---------------- Kernel 2: partial 16-mode DFT ----------------
// grid (B*CHN, 8 chunks), block 256. Accumulate S_re[k]=sum u*cos, S_im[k]=sum u*sin.
#define DFT_CHUNKS 8
__global__ void dft_kernel(const float* __restrict__ u, float* __restrict__ partial)
{
    const int gx = blockIdx.x;          // b*CHN + c
    const int chunk = blockIdx.y;
    const int t = threadIdx.x;
    const float* up = u + (size_t)gx*NN;

    float are[NMODES], aim[NMODES];
    #pragma unroll
    for (int k2=0;k2<NMODES;k2++){ are[k2]=0.f; aim[k2]=0.f; }

    for (int it=0; it<NN/DFT_CHUNKS/256; ++it){
        int j = chunk*(NN/DFT_CHUNKS) + it*256 + t;
        float v = up[j];
        float rev = (float)j * (1.0f/65536.0f);     // exact (pow2 divisor)
        float c1 = __builtin_amdgcn_cosf(rev);      // hw: cos(2*pi*rev)
        float s1 = __builtin_amdgcn_sinf(rev);
        are[0] += v;
        float ck=c1, sk=s1;
        #pragma unroll
        for (int k2=1;k2<NMODES;k2++){
            are[k2] += v*ck;
            aim[k2] += v*sk;
            float cn = ck*c1 - sk*s1;
            sk = sk*c1 + ck*s1;
            ck = cn;
        }
    }
    // wave (64-lane) butterfly reduction
    #pragma unroll
    for (int k2=0;k2<NMODES;k2++){
        for (int off=32; off; off>>=1){
            are[k2] += __shfl_down(are[k2], off, 64);
            aim[k2] += __shfl_down(aim[k2], off, 64);
        }
    }
    __shared__ float red[4][2*NMODES];
    const int wave = t>>6, lane = t&63;
    if (lane==0){
        #pragma unroll
        for (int k2=0;k2<NMODES;k2++){ red[wave][k2]=are[k2]; red[wave][NMODES+k2]=aim[k2]; }
    }
    __syncthreads();
    if (t < 2*NMODES){
        float sum = red[0][t]+red[1][t]+red[2][t]+red[3][t];
        partial[((size_t)gx*DFT_CHUNKS + chunk)*(2*NMODES) + t] = sum;
    }
}

// ---------------- Kernel 3: mix + projection fold (tiny) ----------------
// fin[b,p,k] = sum_i x_ft[b,i,k] * (sum_o proj_w[p,o]*W[i,o,k]),  x_ft = S_re - i*S_im
// coeffs for synthesis: dc = Re(fin0)/N + proj_b ; Cre = 2/N*Re(fin_k) ; Cim = -2/N*Im(fin_k)
__global__ void mix_kernel(const float* __restrict__ partial,
                           const float* __restrict__ sw_r,
                           const float* __restrict__ sw_i,
                           const float* __restrict__ proj_w,
                           const float* __restrict__ proj_b,
                           float* __restrict__ dc,
                           float* __restrict__ cre,
                           float* __restrict__ cim)
{
    int idx = blockIdx.x*256 + threadIdx.x;
    if (idx >= BB*CHN*NMODES) return;
    int k = idx & (NMODES-1);
    int p = (idx >> 4) % CHN;
    int b = idx / (CHN*NMODES);

    float fr = 0.f, fi = 0.f;
    for (int i=0;i<CHN;i++){
        float sre=0.f, sim=0.f;
        for (int c2=0;c2<DFT_CHUNKS;c2++){
            const float* pp = partial + ((size_t)(b*CHN+i)*DFT_CHUNKS + c2)*(2*NMODES);
            sre += pp[k];
            sim += pp[NMODES+k];
        }
        float wpr=0.f, wpi=0.f;
        for (int o=0;o<CHN;o++){
            float pw = proj_w[p*CHN+o];
            wpr += pw * sw_r[((size_t)i*CHN+o)*NMODES + k];
            wpi += pw * sw_i[((size_t)i*CHN+o)*NMODES + k];
        }
        // (sre - i*sim)*(wpr + i*wpi)
        fr += sre*wpr + sim*wpi;
        fi += sre*wpi - sim*wpr;
    }
    const float invN = 1.0f/(float)NN;
    int bp = b*CHN + p;
    if (k==0) dc[bp] = fr*invN + proj_b[p];
    cre[bp*NMODES + k] =  2.0f*invN*fr;
    cim[bp*NMODES + k] = -2.0f*invN*fi;
}

// ---------------- Kernel 4: 16-mode synthesis ----------------
// out[b,p,j] = dc + sum_{k=1..15} Cre[k]*cos(2*pi*k*j/N) + Cim[k]*sin(2*pi*k*j/N)
__global__ void synth_kernel(const float* __restrict__ dc,
                             const float* __restrict__ cre,
                             const float* __restrict__ cim,
                             float* __restrict__ out)
{
    const int bp = blockIdx.x;       // b*CHN + p
    const int chunk = blockIdx.y;
    const int t = threadIdx.x;
    float dcv = dc[bp];
    float cr[NMODES], ci[NMODES];
    #pragma unroll
    for (int k2=1;k2<NMODES;k2++){ cr[k2]=cre[bp*NMODES+k2]; ci[k2]=cim[bp*NMODES+k2]; }

    float* op = out + (size_t)bp*NN;
    for (int it=0; it<NN/DFT_CHUNKS/256; ++it){
        int j = chunk*(NN/DFT_CHUNKS) + it*256 + t;
        float rev = (float)j * (1.0f/65536.0f);
        float c1 = __builtin_amdgcn_cosf(rev);
        float s1 = __builtin_amdgcn_sinf(rev);
        float acc = dcv;
        float ck=c1, sk=s1;
        #pragma unroll
        for (int k2=1;k2<NMODES;k2++){
            acc += cr[k2]*ck + ci[k2]*sk;
            float cn = ck*c1 - sk*s1;
            sk = sk*c1 + ck*s1;
            ck = cn;
        }
        op[j] = acc;
    }
}

extern "C" void kernel_launch(void* const* d_in, const int* in_sizes, int n_in,
                              void* d_out, int out_size, void* d_ws, size_t ws_size,
                              hipStream_t stream) {
    const float* u0     = (const float*)d_in[0];
    const float* tspan  = (const float*)d_in[1];
    const float* conv_w = (const float*)d_in[2];
    const float* conv_b = (const float*)d_in[3];
    const float* sw_r   = (const float*)d_in[4];
    const float* sw_i   = (const float*)d_in[5];
    const float* proj_w = (const float*)d_in[6];
    const float* proj_b = (const float*)d_in[7];
    float* out = (float*)d_out;

    // ws layout (floats): dc[192] | cre[3072] | cim[3072] | pad | partial[49152]
    float* wsf = (float*)d_ws;
    float* dc      = wsf;
    float* cre     = wsf + 192;
    float* cim     = wsf + 192 + 3072;
    float* partial = wsf + 8192;

    // K1: fused RK4 ODE -> u_final staged in d_out (exactly B*CHN*NN floats)
    ode_kernel<<<dim3(NTILES, BB), T1, 0, stream>>>(u0, tspan, conv_w, conv_b, out);
    // K2: 16-mode partial DFT of u_final
    dft_kernel<<<dim3(BB*CHN, DFT_CHUNKS), 256, 0, stream>>>(out, partial);
    // K3: chunk-sum + spectral mix + projection fold -> synthesis coeffs
    mix_kernel<<<dim3((BB*CHN*NMODES + 255)/256), 256, 0, stream>>>(
        partial, sw_r, sw_i, proj_w, proj_b, dc, cre, cim);
    // K4: synthesis overwrites d_out with final output
    synth_kernel<<<dim3(BB*CHN, DFT_CHUNKS), 256, 0, stream>>>(dc, cre, cim, out);
}

// Round 2
// 493.839 us; speedup vs baseline: 1.1235x; 1.1235x over previous
//
#include <hip/hip_runtime.h>

#define CHN 6
#define NN 65536
#define BB 32
#define NMODES 16

// ---------------- Kernel 1: fused RK4 ODE ----------------
// block = 256 threads, 4 contiguous points/thread -> 1024-pt extended tile,
// 28-pt halo each side (28 dyn evals each shrink validity by 1), central 968.
#define T1 256
#define P1 4
#define EXT1 (T1*P1)            // 1024
#define HALO1 28
#define TILE1 (EXT1 - 2*HALO1)  // 968
#define NTILES ((NN + TILE1 - 1) / TILE1)  // 68

__device__ __forceinline__ float fast_tanhf(float x){
    // tanh(x) = 1 - 2/(exp(2x)+1); exp(2x) = 2^(x*2*log2(e))
    float e = __builtin_amdgcn_exp2f(x * 2.885390081777926815f);
    float r = __builtin_amdgcn_rcpf(e + 1.0f);
    return 1.0f - 2.0f * r;
}

// __launch_bounds__(256, 2): 2 waves/EU min -> VGPR cap 256. Without this the
// allocator capped at 64 VGPRs and spilled ~70 regs of RK4 state to scratch
// (R1 rocprof: WRITE_SIZE 468 MB vs 50 MB ideal). State needs ~130 VGPRs.
__global__ __launch_bounds__(256, 2)
void ode_kernel(const float* __restrict__ u0,
                const float* __restrict__ tspan,
                const float* __restrict__ cw,
                const float* __restrict__ cb,
                float* __restrict__ uout)
{
    // double-buffered edge-exchange arrays (first/last point of each thread's chunk)
    __shared__ float eF[2][CHN][T1];
    __shared__ float eL[2][CHN][T1];

    const int t = threadIdx.x;
    const int tile = blockIdx.x;
    const int b = blockIdx.y;
    const int j0 = tile*TILE1 - HALO1 + t*P1;     // global index of this thread's chunk
    // chunks are 4-aligned and N%4==0 -> chunk wholly in or out of domain
    const float m = (j0 >= 0 && j0 < NN) ? 1.0f : 0.0f;

    float u[CHN][P1], s[CHN][P1], acc[CHN][P1], k[CHN][P1];

    #pragma unroll
    for (int c=0;c<CHN;c++){
        float4 v = make_float4(0.f,0.f,0.f,0.f);
        if (m != 0.0f) v = *(const float4*)(u0 + ((size_t)(b*CHN+c))*NN + j0);
        u[c][0]=v.x; u[c][1]=v.y; u[c][2]=v.z; u[c][3]=v.w;
        s[c][0]=v.x; s[c][1]=v.y; s[c][2]=v.z; s[c][3]=v.w;
    }

    int buf = 0;
    for (int st=0; st<7; ++st){
        float dt  = tspan[st+1] - tspan[st];
        float hdt = 0.5f*dt;
        float dt6 = dt*(1.0f/6.0f);
        #pragma unroll
        for (int stage=0; stage<4; ++stage){
            // publish edges of current stage input s
            #pragma unroll
            for (int c=0;c<CHN;c++){ eF[buf][c][t]=s[c][0]; eL[buf][c][t]=s[c][P1-1]; }
            __syncthreads();
            const int tl = (t==0)?0:(t-1);
            const int tr = (t==T1-1)?(T1-1):(t+1);
            float vL[CHN], vR[CHN];
            #pragma unroll
            for (int c=0;c<CHN;c++){ vL[c]=eL[buf][c][tl]; vR[c]=eF[buf][c][tr]; }
            buf ^= 1;

            // conv1d k=3 (cross-correlation, zero pad), channels 6->6, + bias
            #pragma unroll
            for (int o=0;o<CHN;o++){
                float bo = cb[o];
                #pragma unroll
                for (int j=0;j<P1;j++) k[o][j] = bo;
            }
            #pragma unroll
            for (int i=0;i<CHN;i++){
                float a0=vL[i], b0=s[i][0], b1=s[i][1], b2=s[i][2], b3=s[i][3], a4=vR[i];
                #pragma unroll
                for (int o=0;o<CHN;o++){
                    float w0=cw[(o*CHN+i)*3+0];
                    float w1=cw[(o*CHN+i)*3+1];
                    float w2=cw[(o*CHN+i)*3+2];
                    k[o][0] += w0*a0 + w1*b0 + w2*b1;
                    k[o][1] += w0*b0 + w1*b1 + w2*b2;
                    k[o][2] += w0*b1 + w1*b2 + w2*b3;
                    k[o][3] += w0*b2 + w1*b3 + w2*a4;
                }
            }
            #pragma unroll
            for (int o=0;o<CHN;o++)
                #pragma unroll
                for (int j=0;j<P1;j++)
                    k[o][j] = fast_tanhf(k[o][j]);

            // RK4 stage update (m zeroes out-of-domain points -> correct zero padding)
            if (stage==0){
                #pragma unroll
                for (int c=0;c<CHN;c++)
                    #pragma unroll
                    for (int j=0;j<P1;j++){
                        acc[c][j] = k[c][j];
                        s[c][j] = m*(u[c][j] + hdt*k[c][j]);
                    }
            } else if (stage==1){
                #pragma unroll
                for (int c=0;c<CHN;c++)
                    #pragma unroll
                    for (int j=0;j<P1;j++){
                        acc[c][j] += 2.0f*k[c][j];
                        s[c][j] = m*(u[c][j] + hdt*k[c][j]);
                    }
            } else if (stage==2){
                #pragma unroll
                for (int c=0;c<CHN;c++)
                    #pragma unroll
                    for (int j=0;j<P1;j++){
                        acc[c][j] += 2.0f*k[c][j];
                        s[c][j] = m*(u[c][j] + dt*k[c][j]);
                    }
            } else {
                #pragma unroll
                for (int c=0;c<CHN;c++)
                    #pragma unroll
                    for (int j=0;j<P1;j++){
                        u[c][j] = m*(u[c][j] + dt6*(acc[c][j] + k[c][j]));
                        s[c][j] = u[c][j];
                    }
            }
        }
    }

    // store central region [HALO1, EXT1-HALO1) -> threads 7..248, clip to N
    if (t >= HALO1/P1 && t < (EXT1-HALO1)/P1 && j0 < NN){
        #pragma unroll
        for (int c=0;c<CHN;c++){
            float4 v = make_float4(u[c][0],u[c][1],u[c][2],u[c][3]);
            *(float4*)(uout + ((size_t)(b*CHN+c))*NN + j0) = v;
        }
    }
}

// ---------------- Kernel 2: partial 16-mode DFT ----------------
// grid (B*CHN, 8 chunks), block 256. Accumulate S_re[k]=sum u*cos, S_im[k]=sum u*sin.
#define DFT_CHUNKS 8
__global__ void dft_kernel(const float* __restrict__ u, float* __restrict__ partial)
{
    const int gx = blockIdx.x;          // b*CHN + c
    const int chunk = blockIdx.y;
    const int t = threadIdx.x;
    const float* up = u + (size_t)gx*NN;

    float are[NMODES], aim[NMODES];
    #pragma unroll
    for (int k2=0;k2<NMODES;k2++){ are[k2]=0.f; aim[k2]=0.f; }

    for (int it=0; it<NN/DFT_CHUNKS/256; ++it){
        int j = chunk*(NN/DFT_CHUNKS) + it*256 + t;
        float v = up[j];
        float rev = (float)j * (1.0f/65536.0f);     // exact (pow2 divisor)
        float c1 = __builtin_amdgcn_cosf(rev);      // hw: cos(2*pi*rev)
        float s1 = __builtin_amdgcn_sinf(rev);
        are[0] += v;
        float ck=c1, sk=s1;
        #pragma unroll
        for (int k2=1;k2<NMODES;k2++){
            are[k2] += v*ck;
            aim[k2] += v*sk;
            float cn = ck*c1 - sk*s1;
            sk = sk*c1 + ck*s1;
            ck = cn;
        }
    }
    // wave (64-lane) butterfly reduction
    #pragma unroll
    for (int k2=0;k2<NMODES;k2++){
        for (int off=32; off; off>>=1){
            are[k2] += __shfl_down(are[k2], off, 64);
            aim[k2] += __shfl_down(aim[k2], off, 64);
        }
    }
    __shared__ float red[4][2*NMODES];
    const int wave = t>>6, lane = t&63;
    if (lane==0){
        #pragma unroll
        for (int k2=0;k2<NMODES;k2++){ red[wave][k2]=are[k2]; red[wave][NMODES+k2]=aim[k2]; }
    }
    __syncthreads();
    if (t < 2*NMODES){
        float sum = red[0][t]+red[1][t]+red[2][t]+red[3][t];
        partial[((size_t)gx*DFT_CHUNKS + chunk)*(2*NMODES) + t] = sum;
    }
}

// ---------------- Kernel 3: mix + projection fold (tiny) ----------------
// fin[b,p,k] = sum_i x_ft[b,i,k] * (sum_o proj_w[p,o]*W[i,o,k]),  x_ft = S_re - i*S_im
// coeffs for synthesis: dc = Re(fin0)/N + proj_b ; Cre = 2/N*Re(fin_k) ; Cim = -2/N*Im(fin_k)
__global__ void mix_kernel(const float* __restrict__ partial,
                           const float* __restrict__ sw_r,
                           const float* __restrict__ sw_i,
                           const float* __restrict__ proj_w,
                           const float* __restrict__ proj_b,
                           float* __restrict__ dc,
                           float* __restrict__ cre,
                           float* __restrict__ cim)
{
    int idx = blockIdx.x*256 + threadIdx.x;
    if (idx >= BB*CHN*NMODES) return;
    int k = idx & (NMODES-1);
    int p = (idx >> 4) % CHN;
    int b = idx / (CHN*NMODES);

    float fr = 0.f, fi = 0.f;
    for (int i=0;i<CHN;i++){
        float sre=0.f, sim=0.f;
        for (int c2=0;c2<DFT_CHUNKS;c2++){
            const float* pp = partial + ((size_t)(b*CHN+i)*DFT_CHUNKS + c2)*(2*NMODES);
            sre += pp[k];
            sim += pp[NMODES+k];
        }
        float wpr=0.f, wpi=0.f;
        for (int o=0;o<CHN;o++){
            float pw = proj_w[p*CHN+o];
            wpr += pw * sw_r[((size_t)i*CHN+o)*NMODES + k];
            wpi += pw * sw_i[((size_t)i*CHN+o)*NMODES + k];
        }
        // (sre - i*sim)*(wpr + i*wpi)
        fr += sre*wpr + sim*wpi;
        fi += sre*wpi - sim*wpr;
    }
    const float invN = 1.0f/(float)NN;
    int bp = b*CHN + p;
    if (k==0) dc[bp] = fr*invN + proj_b[p];
    cre[bp*NMODES + k] =  2.0f*invN*fr;
    cim[bp*NMODES + k] = -2.0f*invN*fi;
}

// ---------------- Kernel 4: 16-mode synthesis ----------------
// out[b,p,j] = dc + sum_{k=1..15} Cre[k]*cos(2*pi*k*j/N) + Cim[k]*sin(2*pi*k*j/N)
__global__ void synth_kernel(const float* __restrict__ dc,
                             const float* __restrict__ cre,
                             const float* __restrict__ cim,
                             float* __restrict__ out)
{
    const int bp = blockIdx.x;       // b*CHN + p
    const int chunk = blockIdx.y;
    const int t = threadIdx.x;
    float dcv = dc[bp];
    float cr[NMODES], ci[NMODES];
    #pragma unroll
    for (int k2=1;k2<NMODES;k2++){ cr[k2]=cre[bp*NMODES+k2]; ci[k2]=cim[bp*NMODES+k2]; }

    float* op = out + (size_t)bp*NN;
    for (int it=0; it<NN/DFT_CHUNKS/256; ++it){
        int j = chunk*(NN/DFT_CHUNKS) + it*256 + t;
        float rev = (float)j * (1.0f/65536.0f);
        float c1 = __builtin_amdgcn_cosf(rev);
        float s1 = __builtin_amdgcn_sinf(rev);
        float acc = dcv;
        float ck=c1, sk=s1;
        #pragma unroll
        for (int k2=1;k2<NMODES;k2++){
            acc += cr[k2]*ck + ci[k2]*sk;
            float cn = ck*c1 - sk*s1;
            sk = sk*c1 + ck*s1;
            ck = cn;
        }
        op[j] = acc;
    }
}

extern "C" void kernel_launch(void* const* d_in, const int* in_sizes, int n_in,
                              void* d_out, int out_size, void* d_ws, size_t ws_size,
                              hipStream_t stream) {
    const float* u0     = (const float*)d_in[0];
    const float* tspan  = (const float*)d_in[1];
    const float* conv_w = (const float*)d_in[2];
    const float* conv_b = (const float*)d_in[3];
    const float* sw_r   = (const float*)d_in[4];
    const float* sw_i   = (const float*)d_in[5];
    const float* proj_w = (const float*)d_in[6];
    const float* proj_b = (const float*)d_in[7];
    float* out = (float*)d_out;

    // ws layout (floats): dc[192] | cre[3072] | cim[3072] | pad | partial[49152]
    float* wsf = (float*)d_ws;
    float* dc      = wsf;
    float* cre     = wsf + 192;
    float* cim     = wsf + 192 + 3072;
    float* partial = wsf + 8192;

    // K1: fused RK4 ODE -> u_final staged in d_out (exactly B*CHN*NN floats)
    ode_kernel<<<dim3(NTILES, BB), T1, 0, stream>>>(u0, tspan, conv_w, conv_b, out);
    // K2: 16-mode partial DFT of u_final
    dft_kernel<<<dim3(BB*CHN, DFT_CHUNKS), 256, 0, stream>>>(out, partial);
    // K3: chunk-sum + spectral mix + projection fold -> synthesis coeffs
    mix_kernel<<<dim3((BB*CHN*NMODES + 255)/256), 256, 0, stream>>>(
        partial, sw_r, sw_i, proj_w, proj_b, dc, cre, cim);
    // K4: synthesis overwrites d_out with final output
    synth_kernel<<<dim3(BB*CHN, DFT_CHUNKS), 256, 0, stream>>>(dc, cre, cim, out);
}